// Round 7
// baseline (381.812 us; speedup 1.0000x reference)
//
#include <hip/hip_runtime.h>
#include <hip/hip_bf16.h>

#define T 128
#define CIN 128
#define C 256
#define NBE 1024  // B*E = 4*256

typedef short bf8_t __attribute__((ext_vector_type(8)));
typedef short s4_t __attribute__((ext_vector_type(4)));
typedef float f4_t __attribute__((ext_vector_type(4)));

__device__ inline short f2bf(float f) {
  union { float f; unsigned u; } v; v.f = f;
  unsigned r = v.u + 0x7FFFu + ((v.u >> 16) & 1u);
  return (short)(r >> 16);
}
__device__ inline float bf2f(short s) {
  union { unsigned u; float f; } v; v.u = ((unsigned)(unsigned short)s) << 16;
  return v.f;
}
__device__ inline f4_t mfma16(bf8_t a, bf8_t b, f4_t c) {
  return __builtin_amdgcn_mfma_f32_16x16x32_bf16(a, b, c, 0, 0, 0);
}
// LDS bf16 tile frag load, XOR-swizzled rows: short index col ^ ((row&7)<<3).
__device__ inline bf8_t lds_frag(const short* base, int row, int kcol, int rowc) {
  return *reinterpret_cast<const bf8_t*>(base + row * rowc + (kcol ^ ((row & 7) << 3)));
}

__global__ void prep_weights(const float* __restrict__ Wp, const float* __restrict__ Wb,
                             const float* __restrict__ Wg, const float* __restrict__ Wd,
                             short* __restrict__ ws) {
  int i = blockIdx.x * 256 + threadIdx.x;  // grid 256*256 = 65536
  if (i < 32768) ws[i] = f2bf(Wp[i]);      // Wp [256][128]
  ws[32768 + i]  = f2bf(Wb[i]);            // Wb [256][256]
  ws[98304 + i]  = f2bf(Wg[i]);
  ws[163840 + i] = f2bf(Wd[i]);
}

__global__ __launch_bounds__(1024, 4) void fused_ssm(
    const float* __restrict__ xe, const short* __restrict__ wgt,
    const float* __restrict__ bp, const float* __restrict__ a_param,
    const float* __restrict__ bb, const float* __restrict__ bg,
    const float* __restrict__ bd, const float* __restrict__ gamma,
    const float* __restrict__ beta, const float* __restrict__ rmean,
    const float* __restrict__ rvar, float* __restrict__ out) {
  // lds[0] = x tile (bf16, swizzled). lds[1] = xe staging, then u/S.
  // After all GEMMs both die and the 128 KiB is reused as the fp32 out tile.
  __shared__ __align__(16) short lds[2][T * C];
  float* fbuf = reinterpret_cast<float*>(lds);

  const int tid = threadIdx.x;
  const int lane = tid & 63;
  const int w = tid >> 6;    // 0..15
  const int wr = w >> 2;     // 0..3: rows [wr*32, wr*32+32)
  const int wcg = w & 3;     // 0..3: cols [wcg*64, wcg*64+64)
  const int l15 = lane & 15;
  const int l4 = lane >> 4;  // 0..3
  const int be = blockIdx.x;

  const float* xe_blk = xe + (size_t)be * T * CIN;
  float* out_blk = out + (size_t)be * T * C;

  const short* Wpb = wgt;           // [256][128]  (N-major, K-contig == B^T)
  const short* Wbb = wgt + 32768;   // [256][256]
  const short* Wgb = wgt + 98304;   // [256][256]
  const short* Wdb = wgt + 163840;  // [256][256]

  // ---- stage x_e -> LDS bf16 (swizzled), float4 loads ----
  {
    const float4* xe4 = reinterpret_cast<const float4*>(xe_blk);
#pragma unroll
    for (int j = 0; j < 4; ++j) {
      float4 v = xe4[j * 1024 + tid];
      int fi = j * 4096 + tid * 4;
      int r = fi >> 7, c = fi & 127;
      s4_t p = {f2bf(v.x), f2bf(v.y), f2bf(v.z), f2bf(v.w)};
      *reinterpret_cast<s4_t*>(&lds[1][r * 128 + (c ^ ((r & 7) << 3))]) = p;
    }
  }
  __syncthreads();

  const int row_a0 = wr * 32 + l15;        // A-frag row (mi=0); +16 for mi=1
  const int colbase = wcg * 64 + l15;      // D/B col base (add ni*16)

  f4_t acc[2][4];

  // ================= GEMM1: x = xe @ Wp^T + bp  (K=128) =================
#pragma unroll
  for (int mi = 0; mi < 2; ++mi)
#pragma unroll
    for (int ni = 0; ni < 4; ++ni) acc[mi][ni] = (f4_t)(0.f);

#pragma unroll
  for (int kk = 0; kk < 4; ++kk) {
    int kcol = kk * 32 + l4 * 8;
    bf8_t a0 = lds_frag(lds[1], row_a0, kcol, 128);
    bf8_t a1 = lds_frag(lds[1], row_a0 + 16, kcol, 128);
    bf8_t bfr[4];
#pragma unroll
    for (int ni = 0; ni < 4; ++ni)
      bfr[ni] = *reinterpret_cast<const bf8_t*>(Wpb + (colbase + ni * 16) * 128 + kcol);
#pragma unroll
    for (int ni = 0; ni < 4; ++ni) {
      acc[0][ni] = mfma16(a0, bfr[ni], acc[0][ni]);
      acc[1][ni] = mfma16(a1, bfr[ni], acc[1][ni]);
    }
  }
  // store x (+bp) to lds[0] (bf16, swizzled)
#pragma unroll
  for (int ni = 0; ni < 4; ++ni) {
    int col = colbase + ni * 16;
    float bias = bp[col];
#pragma unroll
    for (int mi = 0; mi < 2; ++mi)
#pragma unroll
      for (int r = 0; r < 4; ++r) {
        int row = wr * 32 + mi * 16 + l4 * 4 + r;
        lds[0][row * 256 + (col ^ ((row & 7) << 3))] = f2bf(acc[mi][ni][r] + bias);
      }
  }
  __syncthreads();  // x visible to all; also: all GEMM1 reads of lds[1] done

  // ================= GEMM2: u = x @ Wb^T + bb  (K=256) =================
#pragma unroll
  for (int mi = 0; mi < 2; ++mi)
#pragma unroll
    for (int ni = 0; ni < 4; ++ni) acc[mi][ni] = (f4_t)(0.f);

#pragma unroll
  for (int kk = 0; kk < 8; ++kk) {
    int kcol = kk * 32 + l4 * 8;
    bf8_t a0 = lds_frag(lds[0], row_a0, kcol, 256);
    bf8_t a1 = lds_frag(lds[0], row_a0 + 16, kcol, 256);
    bf8_t bfr[4];
#pragma unroll
    for (int ni = 0; ni < 4; ++ni)
      bfr[ni] = *reinterpret_cast<const bf8_t*>(Wbb + (colbase + ni * 16) * 256 + kcol);
#pragma unroll
    for (int ni = 0; ni < 4; ++ni) {
      acc[0][ni] = mfma16(a0, bfr[ni], acc[0][ni]);
      acc[1][ni] = mfma16(a1, bfr[ni], acc[1][ni]);
    }
  }
  // store u (+bb) to lds[1]
#pragma unroll
  for (int ni = 0; ni < 4; ++ni) {
    int col = colbase + ni * 16;
    float bias = bb[col];
#pragma unroll
    for (int mi = 0; mi < 2; ++mi)
#pragma unroll
      for (int r = 0; r < 4; ++r) {
        int row = wr * 32 + mi * 16 + l4 * 4 + r;
        lds[1][row * 256 + (col ^ ((row & 7) << 3))] = f2bf(acc[mi][ni][r] + bias);
      }
  }
  __syncthreads();

  // ===== recurrence: s_t = a*s_{t-1} + u_t, in-place u->S, pipelined =====
  if (tid < 256) {
    float a = tanhf(a_param[tid]);
    float s = 0.f;
    float un = bf2f(lds[1][tid]);  // t=0 (swizzle is identity at t&7==0)
#pragma unroll 8
    for (int t = 0; t < 128; ++t) {
      // prefetch u[t+1] before the store so the chain is just the fma
      float unn = (t < 127) ? bf2f(lds[1][(t + 1) * 256 + (tid ^ (((t + 1) & 7) << 3))]) : 0.f;
      s = a * s + un;
      lds[1][t * 256 + (tid ^ ((t & 7) << 3))] = f2bf(s);
      un = unn;
    }
  }
  __syncthreads();

  // ========== GEMM3+4: y = S @ Wg^T + x @ Wd^T  (K=256, shared acc) ======
  // B-frags loaded in two groups of 4 per kk to keep live VGPRs ~80 (<128).
#pragma unroll
  for (int mi = 0; mi < 2; ++mi)
#pragma unroll
    for (int ni = 0; ni < 4; ++ni) acc[mi][ni] = (f4_t)(0.f);

#pragma unroll
  for (int kk = 0; kk < 8; ++kk) {
    int kcol = kk * 32 + l4 * 8;
    bf8_t s0 = lds_frag(lds[1], row_a0, kcol, 256);
    bf8_t s1 = lds_frag(lds[1], row_a0 + 16, kcol, 256);
    {
      bf8_t bgf[4];
#pragma unroll
      for (int ni = 0; ni < 4; ++ni)
        bgf[ni] = *reinterpret_cast<const bf8_t*>(Wgb + (colbase + ni * 16) * 256 + kcol);
#pragma unroll
      for (int ni = 0; ni < 4; ++ni) {
        acc[0][ni] = mfma16(s0, bgf[ni], acc[0][ni]);
        acc[1][ni] = mfma16(s1, bgf[ni], acc[1][ni]);
      }
    }
    bf8_t x0 = lds_frag(lds[0], row_a0, kcol, 256);
    bf8_t x1 = lds_frag(lds[0], row_a0 + 16, kcol, 256);
    {
      bf8_t bdf[4];
#pragma unroll
      for (int ni = 0; ni < 4; ++ni)
        bdf[ni] = *reinterpret_cast<const bf8_t*>(Wdb + (colbase + ni * 16) * 256 + kcol);
#pragma unroll
      for (int ni = 0; ni < 4; ++ni) {
        acc[0][ni] = mfma16(x0, bdf[ni], acc[0][ni]);
        acc[1][ni] = mfma16(x1, bdf[ni], acc[1][ni]);
      }
    }
  }

  // ======= epilogue: +bg+bd, BN(eval), exact GELU, +x — into acc =========
#pragma unroll
  for (int ni = 0; ni < 4; ++ni) {
    int col = colbase + ni * 16;
    float bsum = bg[col] + bd[col];
    float mu = rmean[col];
    float rstd = rsqrtf(rvar[col] + 1e-5f);
    float ga = gamma[col], bt = beta[col];
#pragma unroll
    for (int mi = 0; mi < 2; ++mi)
#pragma unroll
      for (int r = 0; r < 4; ++r) {
        int row = wr * 32 + mi * 16 + l4 * 4 + r;
        float y = acc[mi][ni][r] + bsum;
        y = (y - mu) * rstd * ga + bt;
        float g = 0.5f * y * (1.f + erff(y * 0.70710678118654752f));
        float xv = bf2f(lds[0][row * 256 + (col ^ ((row & 7) << 3))]);
        acc[mi][ni][r] = g + xv;
      }
  }
  __syncthreads();  // everyone done reading lds[0]/lds[1]

  // stage fp32 out tile in LDS (swizzled: col ^ (((row>>2)&3)<<4)), then
  // perfectly-coalesced float4 stores.
#pragma unroll
  for (int ni = 0; ni < 4; ++ni) {
    int col = colbase + ni * 16;
#pragma unroll
    for (int mi = 0; mi < 2; ++mi)
#pragma unroll
      for (int r = 0; r < 4; ++r) {
        int row = wr * 32 + mi * 16 + l4 * 4 + r;  // (row>>2)&3 == l4
        fbuf[row * 256 + (col ^ (l4 << 4))] = acc[mi][ni][r];
      }
  }
  __syncthreads();

  float4* out4 = reinterpret_cast<float4*>(out_blk);
#pragma unroll
  for (int j = 0; j < 8; ++j) {
    int f4i = j * 1024 + tid;
    int row = f4i >> 6;
    int c4 = (f4i & 63) << 2;
    int sc = c4 ^ (((row >> 2) & 3) << 4);
    out4[f4i] = *reinterpret_cast<float4*>(&fbuf[row * 256 + sc]);
  }
}

extern "C" void kernel_launch(void* const* d_in, const int* in_sizes, int n_in,
                              void* d_out, int out_size, void* d_ws, size_t ws_size,
                              hipStream_t stream) {
  const float* xe    = (const float*)d_in[0];
  const float* Wp    = (const float*)d_in[1];
  const float* bp    = (const float*)d_in[2];
  const float* ap    = (const float*)d_in[3];
  const float* Wb    = (const float*)d_in[4];
  const float* bb    = (const float*)d_in[5];
  const float* Wg    = (const float*)d_in[6];
  const float* bg    = (const float*)d_in[7];
  const float* Wd    = (const float*)d_in[8];
  const float* bd    = (const float*)d_in[9];
  const float* gamma = (const float*)d_in[10];
  const float* beta  = (const float*)d_in[11];
  const float* rmean = (const float*)d_in[12];
  const float* rvar  = (const float*)d_in[13];
  float* out = (float*)d_out;
  short* wgt = (short*)d_ws;  // 229376 shorts = 448 KiB of bf16 weights

  prep_weights<<<256, 256, 0, stream>>>(Wp, Wb, Wg, Wd, wgt);
  fused_ssm<<<NBE, 1024, 0, stream>>>(xe, wgt, bp, ap, bb, bg, bd, gamma, beta,
                                      rmean, rvar, out);
}

// Round 9
// 348.610 us; speedup vs baseline: 1.0952x; 1.0952x over previous
//
#include <hip/hip_runtime.h>
#include <hip/hip_bf16.h>

#define T 128
#define CIN 128
#define C 256
#define NBE 1024  // B*E = 4*256

typedef short bf8_t __attribute__((ext_vector_type(8)));
typedef short s4_t __attribute__((ext_vector_type(4)));
typedef float f4_t __attribute__((ext_vector_type(4)));

__device__ inline short f2bf(float f) {
  union { float f; unsigned u; } v; v.f = f;
  unsigned r = v.u + 0x7FFFu + ((v.u >> 16) & 1u);
  return (short)(r >> 16);
}
__device__ inline float bf2f(short s) {
  union { unsigned u; float f; } v; v.u = ((unsigned)(unsigned short)s) << 16;
  return v.f;
}
__device__ inline f4_t mfma16(bf8_t a, bf8_t b, f4_t c) {
  return __builtin_amdgcn_mfma_f32_16x16x32_bf16(a, b, c, 0, 0, 0);
}
// LDS bf16 tile frag load, XOR-swizzled rows: short index col ^ ((row&7)<<3).
__device__ inline bf8_t lds_frag(const short* base, int row, int kcol, int rowc) {
  return *reinterpret_cast<const bf8_t*>(base + row * rowc + (kcol ^ ((row & 7) << 3)));
}

__global__ void prep_weights(const float* __restrict__ Wp, const float* __restrict__ Wb,
                             const float* __restrict__ Wg, const float* __restrict__ Wd,
                             short* __restrict__ ws) {
  int i = blockIdx.x * 256 + threadIdx.x;  // grid 256*256 = 65536
  if (i < 32768) ws[i] = f2bf(Wp[i]);      // Wp [256][128]
  ws[32768 + i]  = f2bf(Wb[i]);            // Wb [256][256]
  ws[98304 + i]  = f2bf(Wg[i]);
  ws[163840 + i] = f2bf(Wd[i]);
}

// amdgpu_waves_per_eu(4,4): the LLVM-honored occupancy attribute. min=4
// waves/EU -> VGPR budget 128 (512/4). __launch_bounds__' 2nd arg was NOT
// honored (r2/r7 both compiled to a 64-VGPR fence -> scratch spills).
__global__ __launch_bounds__(1024) __attribute__((amdgpu_waves_per_eu(4, 4)))
void fused_ssm(
    const float* __restrict__ xe, const short* __restrict__ wgt,
    const float* __restrict__ bp, const float* __restrict__ a_param,
    const float* __restrict__ bb, const float* __restrict__ bg,
    const float* __restrict__ bd, const float* __restrict__ gamma,
    const float* __restrict__ beta, const float* __restrict__ rmean,
    const float* __restrict__ rvar, float* __restrict__ out) {
  // lds[0] = x tile (bf16, swizzled). lds[1] = xe staging, then u/S.
  // After all GEMMs both die and the 128 KiB is reused as the fp32 out tile.
  __shared__ __align__(16) short lds[2][T * C];
  float* fbuf = reinterpret_cast<float*>(lds);

  const int tid = threadIdx.x;
  const int lane = tid & 63;
  const int w = tid >> 6;    // 0..15
  const int wr = w >> 2;     // 0..3: rows [wr*32, wr*32+32)
  const int wcg = w & 3;     // 0..3: cols [wcg*64, wcg*64+64)
  const int l15 = lane & 15;
  const int l4 = lane >> 4;  // 0..3
  const int be = blockIdx.x;

  const float* xe_blk = xe + (size_t)be * T * CIN;
  float* out_blk = out + (size_t)be * T * C;

  const short* Wpb = wgt;           // [256][128]  (N-major, K-contig == B^T)
  const short* Wbb = wgt + 32768;   // [256][256]
  const short* Wgb = wgt + 98304;   // [256][256]
  const short* Wdb = wgt + 163840;  // [256][256]

  // ---- stage x_e -> LDS bf16 (swizzled), float4 loads ----
  {
    const float4* xe4 = reinterpret_cast<const float4*>(xe_blk);
#pragma unroll
    for (int j = 0; j < 4; ++j) {
      float4 v = xe4[j * 1024 + tid];
      int fi = j * 4096 + tid * 4;
      int r = fi >> 7, c = fi & 127;
      s4_t p = {f2bf(v.x), f2bf(v.y), f2bf(v.z), f2bf(v.w)};
      *reinterpret_cast<s4_t*>(&lds[1][r * 128 + (c ^ ((r & 7) << 3))]) = p;
    }
  }
  __syncthreads();

  const int row_a0 = wr * 32 + l15;        // A-frag row (mi=0); +16 for mi=1
  const int colbase = wcg * 64 + l15;      // D/B col base (add ni*16)

  f4_t acc[2][4];

  // ================= GEMM1: x = xe @ Wp^T + bp  (K=128) =================
#pragma unroll
  for (int mi = 0; mi < 2; ++mi)
#pragma unroll
    for (int ni = 0; ni < 4; ++ni) acc[mi][ni] = (f4_t)(0.f);

#pragma unroll
  for (int kk = 0; kk < 4; ++kk) {
    int kcol = kk * 32 + l4 * 8;
    bf8_t a0 = lds_frag(lds[1], row_a0, kcol, 128);
    bf8_t a1 = lds_frag(lds[1], row_a0 + 16, kcol, 128);
    bf8_t bfr[4];
#pragma unroll
    for (int ni = 0; ni < 4; ++ni)
      bfr[ni] = *reinterpret_cast<const bf8_t*>(Wpb + (colbase + ni * 16) * 128 + kcol);
#pragma unroll
    for (int ni = 0; ni < 4; ++ni) {
      acc[0][ni] = mfma16(a0, bfr[ni], acc[0][ni]);
      acc[1][ni] = mfma16(a1, bfr[ni], acc[1][ni]);
    }
  }
  // store x (+bp) to lds[0] (bf16, swizzled)
#pragma unroll
  for (int ni = 0; ni < 4; ++ni) {
    int col = colbase + ni * 16;
    float bias = bp[col];
#pragma unroll
    for (int mi = 0; mi < 2; ++mi)
#pragma unroll
      for (int r = 0; r < 4; ++r) {
        int row = wr * 32 + mi * 16 + l4 * 4 + r;
        lds[0][row * 256 + (col ^ ((row & 7) << 3))] = f2bf(acc[mi][ni][r] + bias);
      }
  }
  __syncthreads();  // x visible to all; also: all GEMM1 reads of lds[1] done

  // ================= GEMM2: u = x @ Wb^T + bb  (K=256) =================
#pragma unroll
  for (int mi = 0; mi < 2; ++mi)
#pragma unroll
    for (int ni = 0; ni < 4; ++ni) acc[mi][ni] = (f4_t)(0.f);

#pragma unroll
  for (int kk = 0; kk < 8; ++kk) {
    int kcol = kk * 32 + l4 * 8;
    bf8_t a0 = lds_frag(lds[0], row_a0, kcol, 256);
    bf8_t a1 = lds_frag(lds[0], row_a0 + 16, kcol, 256);
    bf8_t bfr[4];
#pragma unroll
    for (int ni = 0; ni < 4; ++ni)
      bfr[ni] = *reinterpret_cast<const bf8_t*>(Wbb + (colbase + ni * 16) * 256 + kcol);
#pragma unroll
    for (int ni = 0; ni < 4; ++ni) {
      acc[0][ni] = mfma16(a0, bfr[ni], acc[0][ni]);
      acc[1][ni] = mfma16(a1, bfr[ni], acc[1][ni]);
    }
  }
  // store u (+bb) to lds[1]
#pragma unroll
  for (int ni = 0; ni < 4; ++ni) {
    int col = colbase + ni * 16;
    float bias = bb[col];
#pragma unroll
    for (int mi = 0; mi < 2; ++mi)
#pragma unroll
      for (int r = 0; r < 4; ++r) {
        int row = wr * 32 + mi * 16 + l4 * 4 + r;
        lds[1][row * 256 + (col ^ ((row & 7) << 3))] = f2bf(acc[mi][ni][r] + bias);
      }
  }
  __syncthreads();

  // ===== recurrence: s_t = a*s_{t-1} + u_t, in-place u->S ==============
  // 8-deep prefetch ring: reads issue 8 iters ahead (~100cyc of hiding,
  // covers LDS latency); serial chain is just the fma. unroll 8 keeps all
  // ring indices static (no scratch) and the swizzle XOR constant per slot
  // since (t+8)&7 == t&7.
  if (tid < 256) {
    float a = tanhf(a_param[tid]);
    float s = 0.f;
    float un[8];
#pragma unroll
    for (int j = 0; j < 8; ++j)
      un[j] = bf2f(lds[1][j * 256 + (tid ^ ((j & 7) << 3))]);
#pragma unroll 8
    for (int t = 0; t < 128; ++t) {
      float unn = (t + 8 < 128)
          ? bf2f(lds[1][(t + 8) * 256 + (tid ^ ((t & 7) << 3))]) : 0.f;
      s = a * s + un[0];
      lds[1][t * 256 + (tid ^ ((t & 7) << 3))] = f2bf(s);
#pragma unroll
      for (int j = 0; j < 7; ++j) un[j] = un[j + 1];
      un[7] = unn;
    }
  }
  __syncthreads();

  // ========== GEMM3+4: y = S @ Wg^T + x @ Wd^T  (K=256, shared acc) ======
  // B-frags loaded in two groups of 4 per kk to keep live VGPRs < 128.
#pragma unroll
  for (int mi = 0; mi < 2; ++mi)
#pragma unroll
    for (int ni = 0; ni < 4; ++ni) acc[mi][ni] = (f4_t)(0.f);

#pragma unroll
  for (int kk = 0; kk < 8; ++kk) {
    int kcol = kk * 32 + l4 * 8;
    bf8_t s0 = lds_frag(lds[1], row_a0, kcol, 256);
    bf8_t s1 = lds_frag(lds[1], row_a0 + 16, kcol, 256);
    {
      bf8_t bgf[4];
#pragma unroll
      for (int ni = 0; ni < 4; ++ni)
        bgf[ni] = *reinterpret_cast<const bf8_t*>(Wgb + (colbase + ni * 16) * 256 + kcol);
#pragma unroll
      for (int ni = 0; ni < 4; ++ni) {
        acc[0][ni] = mfma16(s0, bgf[ni], acc[0][ni]);
        acc[1][ni] = mfma16(s1, bgf[ni], acc[1][ni]);
      }
    }
    bf8_t x0 = lds_frag(lds[0], row_a0, kcol, 256);
    bf8_t x1 = lds_frag(lds[0], row_a0 + 16, kcol, 256);
    {
      bf8_t bdf[4];
#pragma unroll
      for (int ni = 0; ni < 4; ++ni)
        bdf[ni] = *reinterpret_cast<const bf8_t*>(Wdb + (colbase + ni * 16) * 256 + kcol);
#pragma unroll
      for (int ni = 0; ni < 4; ++ni) {
        acc[0][ni] = mfma16(x0, bdf[ni], acc[0][ni]);
        acc[1][ni] = mfma16(x1, bdf[ni], acc[1][ni]);
      }
    }
  }

  // ======= epilogue: +bg+bd, BN(eval), exact GELU, +x — into acc =========
#pragma unroll
  for (int ni = 0; ni < 4; ++ni) {
    int col = colbase + ni * 16;
    float bsum = bg[col] + bd[col];
    float mu = rmean[col];
    float rstd = rsqrtf(rvar[col] + 1e-5f);
    float ga = gamma[col], bt = beta[col];
#pragma unroll
    for (int mi = 0; mi < 2; ++mi)
#pragma unroll
      for (int r = 0; r < 4; ++r) {
        int row = wr * 32 + mi * 16 + l4 * 4 + r;
        float y = acc[mi][ni][r] + bsum;
        y = (y - mu) * rstd * ga + bt;
        float g = 0.5f * y * (1.f + erff(y * 0.70710678118654752f));
        float xv = bf2f(lds[0][row * 256 + (col ^ ((row & 7) << 3))]);
        acc[mi][ni][r] = g + xv;
      }
  }
  __syncthreads();  // everyone done reading lds[0]/lds[1]

  // stage fp32 out tile in LDS (swizzled: col ^ (((row>>2)&3)<<4)), then
  // perfectly-coalesced float4 stores.
#pragma unroll
  for (int ni = 0; ni < 4; ++ni) {
    int col = colbase + ni * 16;
#pragma unroll
    for (int mi = 0; mi < 2; ++mi)
#pragma unroll
      for (int r = 0; r < 4; ++r) {
        int row = wr * 32 + mi * 16 + l4 * 4 + r;  // (row>>2)&3 == l4
        fbuf[row * 256 + (col ^ (l4 << 4))] = acc[mi][ni][r];
      }
  }
  __syncthreads();

  float4* out4 = reinterpret_cast<float4*>(out_blk);
#pragma unroll
  for (int j = 0; j < 8; ++j) {
    int f4i = j * 1024 + tid;
    int row = f4i >> 6;
    int c4 = (f4i & 63) << 2;
    int sc = c4 ^ (((row >> 2) & 3) << 4);
    out4[f4i] = *reinterpret_cast<float4*>(&fbuf[row * 256 + sc]);
  }
}

extern "C" void kernel_launch(void* const* d_in, const int* in_sizes, int n_in,
                              void* d_out, int out_size, void* d_ws, size_t ws_size,
                              hipStream_t stream) {
  const float* xe    = (const float*)d_in[0];
  const float* Wp    = (const float*)d_in[1];
  const float* bp    = (const float*)d_in[2];
  const float* ap    = (const float*)d_in[3];
  const float* Wb    = (const float*)d_in[4];
  const float* bb    = (const float*)d_in[5];
  const float* Wg    = (const float*)d_in[6];
  const float* bg    = (const float*)d_in[7];
  const float* Wd    = (const float*)d_in[8];
  const float* bd    = (const float*)d_in[9];
  const float* gamma = (const float*)d_in[10];
  const float* beta  = (const float*)d_in[11];
  const float* rmean = (const float*)d_in[12];
  const float* rvar  = (const float*)d_in[13];
  float* out = (float*)d_out;
  short* wgt = (short*)d_ws;  // 229376 shorts = 448 KiB of bf16 weights

  prep_weights<<<256, 256, 0, stream>>>(Wp, Wb, Wg, Wd, wgt);
  fused_ssm<<<NBE, 1024, 0, stream>>>(xe, wgt, bp, ap, bb, bg, bd, gamma, beta,
                                      rmean, rvar, out);
}